// Round 5
// baseline (455.015 us; speedup 1.0000x reference)
//
#include <hip/hip_runtime.h>

#define NEGV (-10000.0f)

namespace {
constexpr int Bn = 256;   // batch
constexpr int Sn = 1024;  // sequence length
constexpr int Tn = 128;   // tags incl. start/end
constexpr int START_TAG = 126;
constexpr int END_TAG = 127;

typedef _Float16 h2 __attribute__((ext_vector_type(2)));
typedef float f32x2 __attribute__((ext_vector_type(2)));

__device__ __forceinline__ float fdot2u(unsigned int s, unsigned int e, float c) {
  return __builtin_amdgcn_fdot2(__builtin_bit_cast(h2, s), __builtin_bit_cast(h2, e), c, false);
}
__device__ __forceinline__ unsigned int pk16(float x, float y) {
  return __builtin_bit_cast(unsigned int, __builtin_amdgcn_cvt_pkrtz(x, y));
}
template <int CTRL>
__device__ __forceinline__ float dppmax(float x) {
  float y = __int_as_float(
      __builtin_amdgcn_update_dpp(0, __float_as_int(x), CTRL, 0xF, 0xF, false));
  return fmaxf(x, y);
}
// full 64-lane max, result broadcast via readlane (validated sequence from r4)
__device__ __forceinline__ float wave_max64(float m) {
  m = dppmax<0xB1>(m);   // quad_perm xor1
  m = dppmax<0x4E>(m);   // quad_perm xor2
  m = dppmax<0x141>(m);  // row_half_mirror -> 8-groups uniform
  m = dppmax<0x140>(m);  // row_mirror      -> 16-groups uniform
  m = dppmax<0x142>(m);  // row_bcast15
  m = dppmax<0x143>(m);  // row_bcast31     -> lane63 = full max
  return __int_as_float(__builtin_amdgcn_readlane(__float_as_int(m), 63));
}
__device__ __forceinline__ float wave_sum(float v) {
#pragma unroll
  for (int off = 32; off >= 1; off >>= 1) v += __shfl_xor(v, off);
  return v;
}

// ws layout (floats):
//   [0, Bn*Tn)         : a_511 per batch (normalized)
//   [Bn*Tn, 2*Bn*Tn)   : b_511 per batch (normalized)
//   [2*Bn*Tn, +Bn*4)   : per-batch scalars {logoff_a, gold_a, logoff_b, gold_b}

// One WAVE per chain: lane l owns output cols {2l, 2l+1}, reduces full depth 128
// in-lane via v_dot2_f32_f16 (f16 pairs along depth, f32 accumulate). State vec
// lives in 512B LDS (f16), double-buffered; wave-synchronous -> NO barriers.
// Per-step renorm (f16 range) via DPP max; emissions prefetched 2 steps ahead.
__global__ __launch_bounds__(64, 1) void crf_chain(
    const float* __restrict__ em, const int* __restrict__ tags,
    const float* __restrict__ trans, float* __restrict__ ws) {
  const int bid = blockIdx.x;
  const bool isf = (bid < Bn);
  const int b = isf ? bid : (bid - Bn);
  const int l = threadIdx.x;  // 0..63
  const int c0 = 2 * l, c1 = 2 * l + 1;

  __shared__ __align__(16) unsigned int sbuf[2][64];  // 128 f16 per buffer

  const float* embase = em + (size_t)b * Sn * Tn;

  // E fragments: 128 packed-f16 regs. E0[k] = (E[2k][c0], E[2k+1][c0]) etc.
  unsigned int E0[64], E1[64];
  if (isf) {
#pragma unroll
    for (int k = 0; k < 64; ++k) {
      const f32x2 r0 = *(const f32x2*)(trans + (size_t)(2 * k) * Tn + c0);
      const f32x2 r1 = *(const f32x2*)(trans + (size_t)(2 * k + 1) * Tn + c0);
      E0[k] = pk16(__expf(r0.x), __expf(r1.x));
      E1[k] = pk16(__expf(r0.y), __expf(r1.y));
    }
  } else {
#pragma unroll
    for (int k = 0; k < 64; ++k) {
      const f32x2 p0 = *(const f32x2*)(trans + (size_t)c0 * Tn + 2 * k);
      const f32x2 p1 = *(const f32x2*)(trans + (size_t)c1 * Tn + 2 * k);
      E0[k] = pk16(__expf(p0.x), __expf(p0.y));
      E1[k] = pk16(__expf(p1.x), __expf(p1.y));
    }
  }

  // init state
  if (isf) {
    sbuf[0][l] = (l == 63) ? 0x00003C00u : 0u;  // onehot(start=126): f16 1.0 lo
  } else {
    const float v0 = __expf(trans[END_TAG * Tn + c0] - NEGV +
                            embase[(size_t)(Sn - 1) * Tn + c0]);
    const float v1 = __expf(trans[END_TAG * Tn + c1] - NEGV +
                            embase[(size_t)(Sn - 1) * Tn + c1]);
    sbuf[0][l] = pk16(v0, v1);
  }
  float logoff = isf ? 0.f : NEGV;

  const int iters = isf ? (Sn / 2 - 1) : (Sn / 2);  // fwd 511, bwd 512
  // emission prefetch, 2 steps deep (emA: odd steps, emB: even steps)
  f32x2 emA = *(const f32x2*)(embase + (size_t)(isf ? 1 : Sn - 2) * Tn + c0);
  f32x2 emB = *(const f32x2*)(embase + (size_t)(isf ? 2 : Sn - 3) * Tn + c0);

  float nv0 = 0.f, nv1 = 0.f;

  auto step = [&](int n, int rb, int wb, f32x2& emreg) {
    const f32x2 emu = emreg;
    if (n + 2 <= Sn / 2 - 1) {  // last em-consuming step is 511 for both dirs
      const int idx = isf ? (n + 2) : (Sn - 1) - (n + 2);
      emreg = *(const f32x2*)(embase + (size_t)idx * Tn + c0);
    }
    const unsigned int* sv = &sbuf[rb][0];
    float ax0 = 0.f, ax1 = 0.f, ax2 = 0.f, ax3 = 0.f;
    float ay0 = 0.f, ay1 = 0.f, ay2 = 0.f, ay3 = 0.f;
#pragma unroll
    for (int kk = 0; kk < 16; ++kk) {
      const uint4 q = *(const uint4*)(sv + 4 * kk);  // broadcast read
      ax0 = fdot2u(q.x, E0[4 * kk + 0], ax0);
      ay0 = fdot2u(q.x, E1[4 * kk + 0], ay0);
      ax1 = fdot2u(q.y, E0[4 * kk + 1], ax1);
      ay1 = fdot2u(q.y, E1[4 * kk + 1], ay1);
      ax2 = fdot2u(q.z, E0[4 * kk + 2], ax2);
      ay2 = fdot2u(q.z, E1[4 * kk + 2], ay2);
      ax3 = fdot2u(q.w, E0[4 * kk + 3], ax3);
      ay3 = fdot2u(q.w, E1[4 * kk + 3], ay3);
    }
    float v0 = (ax0 + ax1) + (ax2 + ax3);
    float v1 = (ay0 + ay1) + (ay2 + ay3);
    const bool mul = isf || (n < iters);  // bwd last matvec: no emission factor
    if (mul) {
      v0 *= __expf(emu.x);
      v1 *= __expf(emu.y);
    }
    const float m = wave_max64(fmaxf(v0, v1));
    logoff += __logf(m);
    const float sc = __builtin_amdgcn_rcpf(m);
    nv0 = v0 * sc;
    nv1 = v1 * sc;
    sbuf[wb][l] = pk16(nv0, nv1);
  };

  int n = 1;
  for (; n + 1 <= iters; n += 2) {
    step(n, 0, 1, emA);      // odd step: read buf0, write buf1
    step(n + 1, 1, 0, emB);  // even step: read buf1, write buf0
  }
  if (n <= iters) step(n, 0, 1, emA);  // fwd tail (iters=511 odd)

  // store normalized final vector + log-offset
  float* vec_out = ws + (isf ? 0 : Bn * Tn) + b * Tn;
  float* scal = ws + 2 * Bn * Tn + b * 4;
  vec_out[c0] = nv0;
  vec_out[c1] = nv1;
  if (l == 0) scal[isf ? 0 : 2] = logoff;

  // ---- gold path score (each chain covers its half of t) ----
  const int* tg = tags + b * Sn;
  float g = 0.f;
  const int t0 = isf ? 0 : (Sn / 2);
  for (int t = t0 + l; t < t0 + Sn / 2; t += 64) {
    const int tag = tg[t];
    g += embase[(size_t)t * Tn + tag];
    if (isf) {
      if (t < Sn / 2 - 1) g += trans[tag * Tn + tg[t + 1]];
    } else {
      g += trans[tg[t - 1] * Tn + tag];  // covers pairs (511,512)..(1022,1023)
    }
  }
  if (l == 0)
    g += isf ? trans[START_TAG * Tn + tg[0]] : trans[tg[Sn - 1] * Tn + END_TAG];
  g = wave_sum(g);
  if (l == 0) scal[isf ? 1 : 3] = g;
}

__global__ void crf_final(const float* __restrict__ ws, float* __restrict__ out) {
  const int tid = threadIdx.x;  // 256 threads = one per batch
  const float* av = ws + tid * Tn;
  const float* bv = ws + Bn * Tn + tid * Tn;
  const float* scal = ws + 2 * Bn * Tn + tid * 4;
  float dot = 0.f;
#pragma unroll 4
  for (int k = 0; k < Tn / 4; ++k) {
    const float4 a4 = reinterpret_cast<const float4*>(av)[k];
    const float4 b4 = reinterpret_cast<const float4*>(bv)[k];
    dot += a4.x * b4.x + a4.y * b4.y + a4.z * b4.z + a4.w * b4.w;
  }
  const float partition = scal[0] + scal[2] + __logf(dot);
  const float loss = partition - scal[1] - scal[3];
  float ssum = wave_sum(loss);
  __shared__ float r[4];
  if ((tid & 63) == 0) r[tid >> 6] = ssum;
  __syncthreads();
  if (tid == 0) out[0] = (r[0] + r[1] + r[2] + r[3]) * (1.f / Bn);
}

}  // namespace

extern "C" void kernel_launch(void* const* d_in, const int* in_sizes, int n_in,
                              void* d_out, int out_size, void* d_ws, size_t ws_size,
                              hipStream_t stream) {
  (void)in_sizes; (void)n_in; (void)out_size; (void)ws_size;
  const float* em = (const float*)d_in[0];
  const int* tags = (const int*)d_in[1];
  const float* trans = (const float*)d_in[2];
  float* out = (float*)d_out;
  float* ws = (float*)d_ws;

  crf_chain<<<dim3(2 * Bn), dim3(64), 0, stream>>>(em, tags, trans, ws);
  crf_final<<<dim3(1), dim3(256), 0, stream>>>(ws, out);
}

// Round 6
// 431.087 us; speedup vs baseline: 1.0555x; 1.0555x over previous
//
#include <hip/hip_runtime.h>

#define NEGV (-10000.0f)

namespace {
constexpr int Bn = 256;   // batch
constexpr int Sn = 1024;  // sequence length
constexpr int Tn = 128;   // tags incl. start/end
constexpr int START_TAG = 126;
constexpr int END_TAG = 127;

typedef _Float16 h2 __attribute__((ext_vector_type(2)));
typedef float f32x2 __attribute__((ext_vector_type(2)));

__device__ __forceinline__ float fdot2u(unsigned int s, unsigned int e, float c) {
  return __builtin_amdgcn_fdot2(__builtin_bit_cast(h2, s), __builtin_bit_cast(h2, e), c, false);
}
__device__ __forceinline__ unsigned int pk16(float x, float y) {
  return __builtin_bit_cast(unsigned int, __builtin_amdgcn_cvt_pkrtz(x, y));
}
template <int CTRL>
__device__ __forceinline__ float dppmax(float x) {
  float y = __int_as_float(
      __builtin_amdgcn_update_dpp(0, __float_as_int(x), CTRL, 0xF, 0xF, false));
  return fmaxf(x, y);
}
// full 64-lane max, broadcast via readlane (validated r4/r5)
__device__ __forceinline__ float wave_max64(float m) {
  m = dppmax<0xB1>(m);   // quad_perm xor1
  m = dppmax<0x4E>(m);   // quad_perm xor2
  m = dppmax<0x141>(m);  // row_half_mirror
  m = dppmax<0x140>(m);  // row_mirror
  m = dppmax<0x142>(m);  // row_bcast15
  m = dppmax<0x143>(m);  // row_bcast31 -> lane63 = full max
  return __int_as_float(__builtin_amdgcn_readlane(__float_as_int(m), 63));
}
__device__ __forceinline__ float wave_sum(float v) {
#pragma unroll
  for (int off = 32; off >= 1; off >>= 1) v += __shfl_xor(v, off);
  return v;
}

// ws layout (floats):
//   [0, Bn*Tn)         : a_511 per batch (normalized)
//   [Bn*Tn, 2*Bn*Tn)   : b_511 per batch (normalized)
//   [2*Bn*Tn, +Bn*4)   : per-batch scalars {logoff_a, gold_a, logoff_b, gold_b}

#define REP64(M)                                                          \
  M(0) M(1) M(2) M(3) M(4) M(5) M(6) M(7) M(8) M(9) M(10) M(11) M(12)     \
  M(13) M(14) M(15) M(16) M(17) M(18) M(19) M(20) M(21) M(22) M(23) M(24) \
  M(25) M(26) M(27) M(28) M(29) M(30) M(31) M(32) M(33) M(34) M(35) M(36) \
  M(37) M(38) M(39) M(40) M(41) M(42) M(43) M(44) M(45) M(46) M(47) M(48) \
  M(49) M(50) M(51) M(52) M(53) M(54) M(55) M(56) M(57) M(58) M(59) M(60) \
  M(61) M(62) M(63)

// 128 individually NAMED u32 regs -> no alloca, no scratch (r3-r5 all spilled
// array-based E to scratch: VGPR_Count 56/60/88 << array size; ~1000 cyc/step
// of L2-fed reloads). E0_k = f16x2(E[2k][c0], E[2k+1][c0]); E1_k same for c1.
#define EDEF(k) unsigned int E0_##k, E1_##k;
#define EINIT(k)                                                          \
  {                                                                       \
    const float a0 = __expf(trans[(2 * (k)) * sd + cc0]);                 \
    const float a1 = __expf(trans[(2 * (k) + 1) * sd + cc0]);             \
    const float b0 = __expf(trans[(2 * (k)) * sd + cc1]);                 \
    const float b1 = __expf(trans[(2 * (k) + 1) * sd + cc1]);             \
    E0_##k = pk16(a0, a1);                                                \
    E1_##k = pk16(b0, b1);                                                \
  }

#define DOTBLK(kk, i0, i1, i2, i3)                                        \
  {                                                                       \
    const uint4 q = *(const uint4*)(svp + 4 * (kk));                      \
    ax0 = fdot2u(q.x, E0_##i0, ax0); ay0 = fdot2u(q.x, E1_##i0, ay0);     \
    ax1 = fdot2u(q.y, E0_##i1, ax1); ay1 = fdot2u(q.y, E1_##i1, ay1);     \
    ax2 = fdot2u(q.z, E0_##i2, ax2); ay2 = fdot2u(q.z, E1_##i2, ay2);     \
    ax3 = fdot2u(q.w, E0_##i3, ax3); ay3 = fdot2u(q.w, E1_##i3, ay3);     \
  }

#define ALLDOTS                                                           \
  DOTBLK(0, 0, 1, 2, 3)     DOTBLK(1, 4, 5, 6, 7)                         \
  DOTBLK(2, 8, 9, 10, 11)   DOTBLK(3, 12, 13, 14, 15)                     \
  DOTBLK(4, 16, 17, 18, 19) DOTBLK(5, 20, 21, 22, 23)                     \
  DOTBLK(6, 24, 25, 26, 27) DOTBLK(7, 28, 29, 30, 31)                     \
  DOTBLK(8, 32, 33, 34, 35) DOTBLK(9, 36, 37, 38, 39)                     \
  DOTBLK(10, 40, 41, 42, 43) DOTBLK(11, 44, 45, 46, 47)                   \
  DOTBLK(12, 48, 49, 50, 51) DOTBLK(13, 52, 53, 54, 55)                   \
  DOTBLK(14, 56, 57, 58, 59) DOTBLK(15, 60, 61, 62, 63)

// One step. DOMAX=0: const scale 2^-14 (no cross-lane work on serial path).
// DOMAX=1: DPP wave-max renorm. f16 pack always safe: v <= ~3e5 * 2^-14 or v/m.
#define STEP(NN, RB, WB, EMREG, DOMAX)                                    \
  {                                                                       \
    const f32x2 emu = EMREG;                                              \
    if ((NN) + 2 <= Sn / 2 - 1) {                                         \
      const int idx_ = isf ? ((NN) + 2) : (Sn - 1) - ((NN) + 2);          \
      EMREG = *(const f32x2*)(embase + (size_t)idx_ * Tn + c0);           \
    }                                                                     \
    const unsigned int* svp = &sbuf[RB][0];                               \
    float ax0 = 0.f, ax1 = 0.f, ax2 = 0.f, ax3 = 0.f;                     \
    float ay0 = 0.f, ay1 = 0.f, ay2 = 0.f, ay3 = 0.f;                     \
    ALLDOTS                                                               \
    float v0 = (ax0 + ax1) + (ax2 + ax3);                                 \
    float v1 = (ay0 + ay1) + (ay2 + ay3);                                 \
    if (isf || ((NN) < iters)) {                                          \
      v0 *= __expf(emu.x);                                                \
      v1 *= __expf(emu.y);                                                \
    }                                                                     \
    float sc_;                                                            \
    if (DOMAX) {                                                          \
      const float m_ = wave_max64(fmaxf(v0, v1));                         \
      logoff += __logf(m_);                                               \
      sc_ = __builtin_amdgcn_rcpf(m_);                                    \
    } else {                                                              \
      sc_ = 6.103515625e-05f;        /* 2^-14 */                          \
      logoff += 9.704060527839234f;  /* 14*ln2 */                         \
    }                                                                     \
    nv0 = v0 * sc_;                                                       \
    nv1 = v1 * sc_;                                                       \
    sbuf[WB][l] = pk16(nv0, nv1);                                         \
  }

// One WAVE per chain, barrier-free (wave-synchronous LDS). Lane l owns output
// cols {2l, 2l+1}; full depth-128 reduction in-lane via v_dot2_f32_f16.
__global__ __launch_bounds__(64, 1) void crf_chain(
    const float* __restrict__ em, const int* __restrict__ tags,
    const float* __restrict__ trans, float* __restrict__ ws) {
  const int bid = blockIdx.x;
  const bool isf = (bid < Bn);
  const int b = isf ? bid : (bid - Bn);
  const int l = threadIdx.x;  // 0..63
  const int c0 = 2 * l, c1 = 2 * l + 1;

  __shared__ __align__(16) unsigned int sbuf[2][64];  // 128 f16 per buffer

  const float* embase = em + (size_t)b * Sn * Tn;

  // unified strides: E[d][c] = exp(trans[d*sd + c*sc])
  const int sd = isf ? Tn : 1;
  const int sc = isf ? 1 : Tn;
  const int cc0 = c0 * sc, cc1 = c1 * sc;

  REP64(EDEF)
  REP64(EINIT)

  // init state
  if (isf) {
    sbuf[0][l] = (l == 63) ? 0x00003C00u : 0u;  // onehot(start=126): f16 1.0 lo
  } else {
    const float v0 = __expf(trans[END_TAG * Tn + c0] - NEGV +
                            embase[(size_t)(Sn - 1) * Tn + c0]);
    const float v1 = __expf(trans[END_TAG * Tn + c1] - NEGV +
                            embase[(size_t)(Sn - 1) * Tn + c1]);
    sbuf[0][l] = pk16(v0, v1);
  }
  float logoff = isf ? 0.f : NEGV;

  const int iters = isf ? (Sn / 2 - 1) : (Sn / 2);  // fwd 511, bwd 512
  f32x2 emA = *(const f32x2*)(embase + (size_t)(isf ? 1 : Sn - 2) * Tn + c0);
  f32x2 emB = *(const f32x2*)(embase + (size_t)(isf ? 2 : Sn - 3) * Tn + c0);

  float nv0 = 0.f, nv1 = 0.f;

  int n = 1;
  for (; n + 1 <= iters; n += 2) {
    STEP(n, 0, 1, emA, 0)      // odd: read buf0 write buf1, const-scale
    STEP(n + 1, 1, 0, emB, 1)  // even: read buf1 write buf0, max-renorm
  }
  if (n <= iters) STEP(n, 0, 1, emA, 0)  // fwd tail (iters=511 odd)

  // final renormalize + store vector and log-offset
  {
    const float m = wave_max64(fmaxf(nv0, nv1));
    logoff += __logf(m);
    const float rs = __builtin_amdgcn_rcpf(m);
    float* vec_out = ws + (isf ? 0 : Bn * Tn) + b * Tn;
    vec_out[c0] = nv0 * rs;
    vec_out[c1] = nv1 * rs;
  }
  float* scal = ws + 2 * Bn * Tn + b * 4;
  if (l == 0) scal[isf ? 0 : 2] = logoff;

  // ---- gold path score (each chain covers its half of t) ----
  const int* tg = tags + b * Sn;
  float g = 0.f;
  const int t0 = isf ? 0 : (Sn / 2);
  for (int t = t0 + l; t < t0 + Sn / 2; t += 64) {
    const int tag = tg[t];
    g += embase[(size_t)t * Tn + tag];
    if (isf) {
      if (t < Sn / 2 - 1) g += trans[tag * Tn + tg[t + 1]];
    } else {
      g += trans[tg[t - 1] * Tn + tag];  // covers pairs (511,512)..(1022,1023)
    }
  }
  if (l == 0)
    g += isf ? trans[START_TAG * Tn + tg[0]] : trans[tg[Sn - 1] * Tn + END_TAG];
  g = wave_sum(g);
  if (l == 0) scal[isf ? 1 : 3] = g;
}

__global__ void crf_final(const float* __restrict__ ws, float* __restrict__ out) {
  const int tid = threadIdx.x;  // 256 threads = one per batch
  const float* av = ws + tid * Tn;
  const float* bv = ws + Bn * Tn + tid * Tn;
  const float* scal = ws + 2 * Bn * Tn + tid * 4;
  float dot = 0.f;
#pragma unroll 4
  for (int k = 0; k < Tn / 4; ++k) {
    const float4 a4 = reinterpret_cast<const float4*>(av)[k];
    const float4 b4 = reinterpret_cast<const float4*>(bv)[k];
    dot += a4.x * b4.x + a4.y * b4.y + a4.z * b4.z + a4.w * b4.w;
  }
  const float partition = scal[0] + scal[2] + __logf(dot);
  const float loss = partition - scal[1] - scal[3];
  float ssum = wave_sum(loss);
  __shared__ float r[4];
  if ((tid & 63) == 0) r[tid >> 6] = ssum;
  __syncthreads();
  if (tid == 0) out[0] = (r[0] + r[1] + r[2] + r[3]) * (1.f / Bn);
}

}  // namespace

extern "C" void kernel_launch(void* const* d_in, const int* in_sizes, int n_in,
                              void* d_out, int out_size, void* d_ws, size_t ws_size,
                              hipStream_t stream) {
  (void)in_sizes; (void)n_in; (void)out_size; (void)ws_size;
  const float* em = (const float*)d_in[0];
  const int* tags = (const int*)d_in[1];
  const float* trans = (const float*)d_in[2];
  float* out = (float*)d_out;
  float* ws = (float*)d_ws;

  crf_chain<<<dim3(2 * Bn), dim3(64), 0, stream>>>(em, tags, trans, ws);
  crf_final<<<dim3(1), dim3(256), 0, stream>>>(ws, out);
}